// Round 1
// baseline (422.109 us; speedup 1.0000x reference)
//
#include <hip/hip_runtime.h>

// Complex FIR, taps=11, SAME padding, stride 1.
// X: (BATCH, N, 2) fp32 interleaved (re, im) -> treat as float2.
// phi: (TAPS, 2, 1) fp32 -> phi[k*2+0]=real tap, phi[k*2+1]=imag tap.
// out: (BATCH, N, 2) fp32 interleaved -> float2.
// out[b,n] = sum_k X[b, n-5+k] * phi[k]   (complex multiply, zero pad at edges)

constexpr int N_SAMP  = 262144;
constexpr int BATCH   = 128;
constexpr int TAPS    = 11;
constexpr int HALO    = 5;              // (TAPS-1)/2
constexpr int BLOCK   = 256;
constexpr int VEC     = 4;              // complex outputs per thread
constexpr int TILE    = BLOCK * VEC;    // 1024 complex samples per block
constexpr int SMEM_N  = TILE + 2 * HALO; // 1034

__global__ __launch_bounds__(BLOCK)
void fir_complex_kernel(const float2* __restrict__ X,
                        const float*  __restrict__ phi,
                        float2*       __restrict__ out)
{
    __shared__ float2 s[SMEM_N];

    const int tile_idx   = blockIdx.x;
    const int b          = blockIdx.y;
    const int t          = threadIdx.x;
    const int tile_start = tile_idx * TILE;
    const long long row  = (long long)b * N_SAMP;

    // Filter taps: uniform addresses -> scalar loads, live in SGPRs.
    float pr[TAPS], pi[TAPS];
#pragma unroll
    for (int k = 0; k < TAPS; ++k) {
        pr[k] = phi[2 * k + 0];
        pi[k] = phi[2 * k + 1];
    }

    // Stage tile + halo into LDS, zero-padding outside the row.
    const int g0 = tile_start - HALO;
#pragma unroll
    for (int r = 0; r < (SMEM_N + BLOCK - 1) / BLOCK; ++r) {
        const int i = r * BLOCK + t;
        if (i < SMEM_N) {
            const int n = g0 + i;
            float2 v = make_float2(0.0f, 0.0f);
            if ((unsigned)n < (unsigned)N_SAMP) v = X[row + n];
            s[i] = v;
        }
    }
    __syncthreads();

    // Each thread computes VEC outputs at strided positions t + j*BLOCK:
    // lane-consecutive LDS reads (float2 = benign 2-way bank aliasing) and
    // coalesced float2 stores.
#pragma unroll
    for (int j = 0; j < VEC; ++j) {
        const int l = t + j * BLOCK;
        float re = 0.0f, im = 0.0f;
#pragma unroll
        for (int k = 0; k < TAPS; ++k) {
            const float2 v = s[l + k];
            re = fmaf(v.x, pr[k], re);
            re = fmaf(-v.y, pi[k], re);
            im = fmaf(v.x, pi[k], im);
            im = fmaf(v.y, pr[k], im);
        }
        out[row + tile_start + l] = make_float2(re, im);
    }
}

extern "C" void kernel_launch(void* const* d_in, const int* in_sizes, int n_in,
                              void* d_out, int out_size, void* d_ws, size_t ws_size,
                              hipStream_t stream)
{
    const float2* X   = (const float2*)d_in[0];
    const float*  phi = (const float*)d_in[1];
    float2*       out = (float2*)d_out;

    dim3 grid(N_SAMP / TILE, BATCH);   // 256 x 128 = 32768 blocks
    fir_complex_kernel<<<grid, BLOCK, 0, stream>>>(X, phi, out);
}